// Round 1
// baseline (684.669 us; speedup 1.0000x reference)
//
#include <hip/hip_runtime.h>

#define PROP_ALPHA 0.1f
#define PROP_KSTEPS 10

typedef _Float16 half_t;
typedef __attribute__((ext_vector_type(4))) _Float16 half4v;

__device__ inline unsigned int f2h15(float w) {
    half_t h = (half_t)w;
    return (unsigned int)__builtin_bit_cast(unsigned short, h) & 0x7FFFu;
}
__device__ inline float h15_2f(unsigned int bits) {
    half_t h = __builtin_bit_cast(half_t, (unsigned short)(bits & 0x7FFFu));
    return (float)h;
}

template <typename T> struct V4;
template <> struct V4<_Float16> { typedef half4v type; };
template <> struct V4<float>    { typedef float4 type; };

template <typename T>
__device__ inline float4 ld4f(const T* __restrict__ p) {
    typename V4<T>::type v = *reinterpret_cast<const typename V4<T>::type*>(p);
    float4 r;
    r.x = (float)v.x; r.y = (float)v.y; r.z = (float)v.z; r.w = (float)v.w;
    return r;
}

template <typename T>
__device__ inline void st4(T* __restrict__ p, float4 r) {
    typename V4<T>::type v;
    v.x = (T)r.x; v.y = (T)r.y; v.z = (T)r.z; v.w = (T)r.w;
    *reinterpret_cast<typename V4<T>::type*>(p) = v;
}

// ---------------- CSR build ----------------

__global__ void hist_kernel(const int* __restrict__ dst, int* __restrict__ degI, int E) {
    int e = blockIdx.x * blockDim.x + threadIdx.x;
    if (e < E) atomicAdd(&degI[dst[e]], 1);
}

__global__ void dinv_kernel(const int* __restrict__ degI, float* __restrict__ dinv, int N) {
    int i = blockIdx.x * blockDim.x + threadIdx.x;
    if (i < N) {
        float d = (float)(degI[i] + 1);   // + self loop
        dinv[i] = rsqrtf(d);
    }
}

__global__ __launch_bounds__(256) void scan1_kernel(const int* __restrict__ degI,
                                                    int* __restrict__ rowptr,
                                                    int* __restrict__ blockSums, int N) {
    __shared__ int s[256];
    int t = threadIdx.x;
    int idx = blockIdx.x * 256 + t;
    s[t] = (idx < N) ? degI[idx] : 0;
    __syncthreads();
    for (int off = 1; off < 256; off <<= 1) {
        int x = (t >= off) ? s[t - off] : 0;
        __syncthreads();
        s[t] += x;
        __syncthreads();
    }
    if (idx < N) rowptr[idx + 1] = s[t];
    if (t == 255) blockSums[blockIdx.x] = s[255];
    if (blockIdx.x == 0 && t == 0) rowptr[0] = 0;
}

__global__ __launch_bounds__(256) void scan2_kernel(int* __restrict__ blockSums, int nB) {
    __shared__ int s[256];
    int t = threadIdx.x;
    s[t] = (t < nB) ? blockSums[t] : 0;
    __syncthreads();
    for (int off = 1; off < 256; off <<= 1) {
        int x = (t >= off) ? s[t - off] : 0;
        __syncthreads();
        s[t] += x;
        __syncthreads();
    }
    if (t < nB) blockSums[t] = (t == 0) ? 0 : s[t - 1];
}

__global__ void scan3_kernel(int* __restrict__ rowptr, const int* __restrict__ blockSums,
                             int N) {
    int idx = blockIdx.x * 256 + threadIdx.x;
    if (idx < N) rowptr[idx + 1] += blockSums[blockIdx.x];
}

// edata[p] = src<<15 | fp16bits(norm) sans sign — one 4 B store per edge
__global__ void scatter_kernel(const int* __restrict__ src, const int* __restrict__ dst,
                               const int* __restrict__ rowptr, int* __restrict__ rowctr,
                               const float* __restrict__ dinv,
                               int* __restrict__ edata, int E) {
    int e = blockIdx.x * blockDim.x + threadIdx.x;
    if (e < E) {
        int d = dst[e], s = src[e];
        int p = rowptr[d] + atomicAdd(&rowctr[d], 1);
        unsigned int packed = ((unsigned int)s << 15) | f2h15(dinv[s] * dinv[d]);
        __builtin_nontemporal_store((int)packed, &edata[p]);
    }
}

// ---------------- fused MLP: h2 = relu(zx@W3 + v*b3^T)@W4 + b4 ----------------
// zx fp16 in; zsT/ts staged fp16 (LDS ~45 KB -> 3 blocks/CU); compute fp32.
// ts is ROW-MAJOR [32 rows][132 k-stride]; layer-2 reads are scalar broadcast.

__global__ __launch_bounds__(256) void fusedmlp_kernel(const half_t* __restrict__ zx,
                                                       const float* __restrict__ v,
                                                       const float* __restrict__ W3,
                                                       const float* __restrict__ b3,
                                                       const float* __restrict__ W4,
                                                       const float* __restrict__ b4,
                                                       float* __restrict__ h2, int N) {
    __shared__ float Ws[64 * 128];     // 32 KB: W3 [k][128] then W4 [k][64]
    __shared__ half_t zsT[64 * 36];    // [k][row] fp16, padded stride 36
    __shared__ half_t ts[32 * 132];    // [row][k] fp16, padded stride 132
    __shared__ float vs[32];
    int t = threadIdx.x;
    int r0 = blockIdx.x * 32;
    int rows = min(32, N - r0);

    for (int idx = t; idx < 64 * 128; idx += 256) Ws[idx] = W3[idx];
    for (int idx = t; idx < 32 * 64; idx += 256) {
        int r = idx >> 6, c = idx & 63;
        zsT[c * 36 + r] = (r < rows) ? zx[(size_t)(r0 + r) * 64 + c] : (half_t)0.0f;
    }
    if (t < 32) vs[t] = (t < rows) ? v[r0 + t] : 0.0f;
    __syncthreads();

    // ---- layer 1: ts = relu(z @ W3 + v*b3^T) ----
    {
        int cq = t & 31, rq = t >> 5;
        int cb = cq * 4, rb = rq * 4;
        float4 b3v = *reinterpret_cast<const float4*>(&b3[cb]);
        float a[4][4];
        #pragma unroll
        for (int ri = 0; ri < 4; ++ri) {
            float vv = vs[rb + ri];
            a[ri][0] = vv * b3v.x; a[ri][1] = vv * b3v.y;
            a[ri][2] = vv * b3v.z; a[ri][3] = vv * b3v.w;
        }
        #pragma unroll 4
        for (int k = 0; k < 64; ++k) {
            half4v zh = *reinterpret_cast<const half4v*>(&zsT[k * 36 + rb]);
            float z0 = (float)zh.x, z1 = (float)zh.y, z2 = (float)zh.z, z3 = (float)zh.w;
            float4 wq = *reinterpret_cast<const float4*>(&Ws[k * 128 + cb]);
            a[0][0] += z0 * wq.x; a[0][1] += z0 * wq.y;
            a[0][2] += z0 * wq.z; a[0][3] += z0 * wq.w;
            a[1][0] += z1 * wq.x; a[1][1] += z1 * wq.y;
            a[1][2] += z1 * wq.z; a[1][3] += z1 * wq.w;
            a[2][0] += z2 * wq.x; a[2][1] += z2 * wq.y;
            a[2][2] += z2 * wq.z; a[2][3] += z2 * wq.w;
            a[3][0] += z3 * wq.x; a[3][1] += z3 * wq.y;
            a[3][2] += z3 * wq.z; a[3][3] += z3 * wq.w;
        }
        #pragma unroll
        for (int ri = 0; ri < 4; ++ri) {
            half4v o;
            o.x = (half_t)fmaxf(a[ri][0], 0.0f); o.y = (half_t)fmaxf(a[ri][1], 0.0f);
            o.z = (half_t)fmaxf(a[ri][2], 0.0f); o.w = (half_t)fmaxf(a[ri][3], 0.0f);
            *reinterpret_cast<half4v*>(&ts[(rb + ri) * 132 + cb]) = o;
        }
    }
    __syncthreads();
    for (int idx = t; idx < 128 * 64; idx += 256) Ws[idx] = W4[idx];
    __syncthreads();

    // ---- layer 2: h2 = t @ W4 + b4 (row-major ts reads) ----
    {
        int cg = t & 15, rg = t >> 4;
        int cb = cg * 4, rb = rg * 2;
        float4 b4v = *reinterpret_cast<const float4*>(&b4[cb]);
        float a[2][4];
        #pragma unroll
        for (int ri = 0; ri < 2; ++ri) {
            a[ri][0] = b4v.x; a[ri][1] = b4v.y; a[ri][2] = b4v.z; a[ri][3] = b4v.w;
        }
        #pragma unroll 4
        for (int k = 0; k < 128; ++k) {
            float t0 = (float)ts[rb * 132 + k];
            float t1 = (float)ts[(rb + 1) * 132 + k];
            float4 wq = *reinterpret_cast<const float4*>(&Ws[k * 64 + cb]);
            a[0][0] += t0 * wq.x; a[0][1] += t0 * wq.y;
            a[0][2] += t0 * wq.z; a[0][3] += t0 * wq.w;
            a[1][0] += t1 * wq.x; a[1][1] += t1 * wq.y;
            a[1][2] += t1 * wq.z; a[1][3] += t1 * wq.w;
        }
        #pragma unroll
        for (int ri = 0; ri < 2; ++ri) {
            int r = rb + ri;
            if (r < rows) {
                float4 o = {a[ri][0], a[ri][1], a[ri][2], a[ri][3]};
                *reinterpret_cast<float4*>(&h2[(size_t)(r0 + r) * 64 + cb]) = o;
            }
        }
    }
}

// ---------------- propagation ----------------
// NEW layout: wave = 2 nodes; lane -> (edge-group g = lane>>4, channel slice
// c = (lane&15)*4). Each gather is half4 (8 B/lane) covering 4 edges x full
// 128 B row per instruction -> 1/4 the gather instrs, ~1/2 the VALU per edge.
// Cross-group shfl_xor(16/32) reduction once per node (lane&15 invariant).

template <typename TI, bool WITHV>
__device__ inline void round8(const TI* __restrict__ zin, const int* __restrict__ edata,
                              int e, int g, int c,
                              float4& acc, float& vacc,
                              const float* __restrict__ vin, int firstOnes) {
    // group g handles edges e+2g, e+2g+1 (two 4B edata loads, coalesced)
    unsigned int p0 = (unsigned int)edata[e + 2 * g];
    unsigned int p1 = (unsigned int)edata[e + 2 * g + 1];
    int s0 = p0 >> 15, s1 = p1 >> 15;
    float n0 = h15_2f(p0), n1 = h15_2f(p1);
    float4 z0 = ld4f(&zin[(size_t)s0 * 64 + c]);
    float4 z1 = ld4f(&zin[(size_t)s1 * 64 + c]);
    if (WITHV) {
        if (firstOnes) vacc += n0 + n1;
        else           vacc += n0 * vin[s0] + n1 * vin[s1];
    }
    acc.x += n0 * z0.x; acc.y += n0 * z0.y; acc.z += n0 * z0.z; acc.w += n0 * z0.w;
    acc.x += n1 * z1.x; acc.y += n1 * z1.y; acc.z += n1 * z1.z; acc.w += n1 * z1.w;
}

template <typename TI, bool WITHV>
__device__ inline void round4m(const TI* __restrict__ zin, const int* __restrict__ edata,
                               int e, int end, int g, int c,
                               float4& acc, float& vacc,
                               const float* __restrict__ vin, int firstOnes) {
    // masked tail: group g handles edge e+g if it exists
    int idx = e + g;
    bool valid = idx < end;
    if (!valid) idx = end - 1;          // end >= 1 whenever this is called
    unsigned int p = (unsigned int)edata[idx];
    int s = p >> 15;
    float n = valid ? h15_2f(p) : 0.0f;
    float4 z = ld4f(&zin[(size_t)s * 64 + c]);
    if (WITHV) vacc += firstOnes ? n : n * vin[s];   // n==0 masks invalid lanes
    acc.x += n * z.x; acc.y += n * z.y; acc.z += n * z.z; acc.w += n * z.w;
}

template <typename TI, typename TO, bool WITHV>
__global__ __launch_bounds__(256) void prop64_kernel(const TI* __restrict__ zin,
                                                     const float* __restrict__ h,
                                                     const int* __restrict__ rowptr,
                                                     const int* __restrict__ edata,
                                                     const float* __restrict__ dinv,
                                                     TO* __restrict__ zout,
                                                     const float* __restrict__ vin,
                                                     float* __restrict__ vout,
                                                     int N, int firstOnes) {
    int wave = threadIdx.x >> 6;
    int lane = threadIdx.x & 63;
    int g = lane >> 4;              // edge slot 0..3
    int c = (lane & 15) << 2;       // channel base
    int pair = blockIdx.x * 4 + wave;
    int iA = pair * 2;
    if (iA >= N) return;
    iA = __builtin_amdgcn_readfirstlane(iA);
    int iB = iA + 1;
    bool hasB = (iB < N);
    int begA = rowptr[iA];
    int endA = rowptr[iA + 1];
    int endB = hasB ? rowptr[iB + 1] : endA;
    int eA = begA, eB = endA;

    float4 a = {0.f, 0.f, 0.f, 0.f}, b = {0.f, 0.f, 0.f, 0.f};
    float vaccA = 0.f, vaccB = 0.f;

    // paired main loop: 16 edges / iteration, 4 gathers in flight
    while (eA + 8 <= endA && eB + 8 <= endB) {
        round8<TI, WITHV>(zin, edata, eA, g, c, a, vaccA, vin, firstOnes);
        round8<TI, WITHV>(zin, edata, eB, g, c, b, vaccB, vin, firstOnes);
        eA += 8; eB += 8;
    }
    while (eA + 8 <= endA) {
        round8<TI, WITHV>(zin, edata, eA, g, c, a, vaccA, vin, firstOnes);
        eA += 8;
    }
    while (eB + 8 <= endB) {
        round8<TI, WITHV>(zin, edata, eB, g, c, b, vaccB, vin, firstOnes);
        eB += 8;
    }
    while (eA < endA) {
        round4m<TI, WITHV>(zin, edata, eA, endA, g, c, a, vaccA, vin, firstOnes);
        eA += 4;
    }
    while (eB < endB) {
        round4m<TI, WITHV>(zin, edata, eB, endB, g, c, b, vaccB, vin, firstOnes);
        eB += 4;
    }

    // cross-group reduction: xor 16 / xor 32 keep (lane&15) -> channel slice fixed
    #pragma unroll
    for (int m = 16; m <= 32; m <<= 1) {
        a.x += __shfl_xor(a.x, m); a.y += __shfl_xor(a.y, m);
        a.z += __shfl_xor(a.z, m); a.w += __shfl_xor(a.w, m);
        b.x += __shfl_xor(b.x, m); b.y += __shfl_xor(b.y, m);
        b.z += __shfl_xor(b.z, m); b.w += __shfl_xor(b.w, m);
        if (WITHV) { vaccA += __shfl_xor(vaccA, m); vaccB += __shfl_xor(vaccB, m); }
    }

    // epilogue: lanes 0-15 write node A, lanes 16-31 write node B
    if (lane < 32) {
        bool isA = (lane < 16);
        if (isA || hasB) {
            int node = isA ? iA : iB;
            float4 acc = isA ? a : b;
            int cw = (lane & 15) << 2;
            size_t base = (size_t)node * 64 + cw;
            float di = dinv[node];
            float dd = di * di;
            float4 self = ld4f(&zin[base]);
            float4 hh = *reinterpret_cast<const float4*>(&h[base]);
            float4 r;
            r.x = (1.0f - PROP_ALPHA) * (acc.x + dd * self.x) + PROP_ALPHA * hh.x;
            r.y = (1.0f - PROP_ALPHA) * (acc.y + dd * self.y) + PROP_ALPHA * hh.y;
            r.z = (1.0f - PROP_ALPHA) * (acc.z + dd * self.z) + PROP_ALPHA * hh.z;
            r.w = (1.0f - PROP_ALPHA) * (acc.w + dd * self.w) + PROP_ALPHA * hh.w;
            st4(&zout[base], r);
            if (WITHV && (lane & 15) == 0) {
                float selfv = firstOnes ? 1.0f : vin[node];
                float vacc = isA ? vaccA : vaccB;
                vout[node] = (1.0f - PROP_ALPHA) * (vacc + dd * selfv) + PROP_ALPHA;
            }
        }
    }
}

// ---------------- launch ----------------

extern "C" void kernel_launch(void* const* d_in, const int* in_sizes, int n_in,
                              void* d_out, int out_size, void* d_ws, size_t ws_size,
                              hipStream_t stream) {
    const float* x  = (const float*)d_in[0];
    const int*   ei = (const int*)d_in[1];
    const float* W3 = (const float*)d_in[2];
    const float* b3 = (const float*)d_in[3];
    const float* W4 = (const float*)d_in[4];
    const float* b4 = (const float*)d_in[5];
    float* out = (float*)d_out;

    int N = in_sizes[0] / 64;   // IN_CH = 64
    int E = in_sizes[1] / 2;
    const int* srcA = ei;
    const int* dstA = ei + E;

    char* ws = (char*)d_ws;
    size_t off = 0;
    auto alloc = [&](size_t bytes) -> void* {
        void* p = ws + off;
        off = (off + bytes + 255) & ~(size_t)255;
        return p;
    };

    int nScanB = (N + 255) / 256;

    int*    degI   = (int*)alloc((size_t)N * 4);
    int*    rowptr = (int*)alloc(((size_t)N + 1) * 4);
    int*    rowctr = (int*)alloc((size_t)N * 4);
    int*    bsums  = (int*)alloc((size_t)nScanB * 4);
    float*  dinv   = (float*)alloc((size_t)N * 4);
    int*    edata  = (int*)alloc((size_t)E * 4);
    float*  vA     = (float*)alloc((size_t)N * 4);
    float*  vB     = (float*)alloc((size_t)N * 4);
    half_t* z16A   = (half_t*)alloc((size_t)N * 64 * 2);
    half_t* z16B   = (half_t*)alloc((size_t)N * 64 * 2);
    float*  hbuf   = (float*)alloc((size_t)N * 64 * 4);

    hipMemsetAsync(degI, 0, (size_t)N * 4, stream);
    hipMemsetAsync(rowctr, 0, (size_t)N * 4, stream);

    // --- CSR build ---
    hist_kernel<<<(E + 255) / 256, 256, 0, stream>>>(dstA, degI, E);
    dinv_kernel<<<(N + 255) / 256, 256, 0, stream>>>(degI, dinv, N);
    scan1_kernel<<<nScanB, 256, 0, stream>>>(degI, rowptr, bsums, N);
    scan2_kernel<<<1, 256, 0, stream>>>(bsums, nScanB);
    scan3_kernel<<<nScanB, 256, 0, stream>>>(rowptr, bsums, N);
    scatter_kernel<<<(E + 255) / 256, 256, 0, stream>>>(srcA, dstA, rowptr, rowctr,
                                                        dinv, edata, E);

    int nPairs = (N + 1) / 2;
    int propBlocks = (nPairs + 3) / 4;

    // --- prop1: zx = M*x, z fp16 between steps, fused v = M*ones ---
    for (int s = 0; s < PROP_KSTEPS; ++s) {
        const float* vi = (s & 1) ? vA : vB;   // s0: unused (firstOnes)
        float*       vo = (s & 1) ? vB : vA;
        if (s == 0) vi = vB;
        if (s == 0) {
            prop64_kernel<float, half_t, true><<<propBlocks, 256, 0, stream>>>(
                x, x, rowptr, edata, dinv, z16A, vi, vo, N, 1);
        } else {
            const half_t* in = (s & 1) ? z16A : z16B;
            half_t*       o  = (s & 1) ? z16B : z16A;
            prop64_kernel<half_t, half_t, true><<<propBlocks, 256, 0, stream>>>(
                in, x, rowptr, edata, dinv, o, vi, vo, N, 0);
        }
    }
    // zx (fp16) in z16B, v in vB

    // --- h2 = relu(zx@W3 + v*b3^T)@W4 + b4 ---
    fusedmlp_kernel<<<(N + 31) / 32, 256, 0, stream>>>(z16B, vB, W3, b3, W4, b4, hbuf, N);

    // --- prop2: out = M*h2 ---
    for (int s = 0; s < PROP_KSTEPS; ++s) {
        if (s == 0) {
            prop64_kernel<float, half_t, false><<<propBlocks, 256, 0, stream>>>(
                hbuf, hbuf, rowptr, edata, dinv, z16A, nullptr, nullptr, N, 0);
        } else if (s == PROP_KSTEPS - 1) {
            prop64_kernel<half_t, float, false><<<propBlocks, 256, 0, stream>>>(
                z16A, hbuf, rowptr, edata, dinv, out, nullptr, nullptr, N, 0);
        } else {
            const half_t* in = (s & 1) ? z16A : z16B;
            half_t*       o  = (s & 1) ? z16B : z16A;
            prop64_kernel<half_t, half_t, false><<<propBlocks, 256, 0, stream>>>(
                in, hbuf, rowptr, edata, dinv, o, nullptr, nullptr, N, 0);
        }
    }
}

// Round 2
// 679.286 us; speedup vs baseline: 1.0079x; 1.0079x over previous
//
#include <hip/hip_runtime.h>

#define PROP_ALPHA 0.1f
#define PROP_KSTEPS 10

typedef _Float16 half_t;
typedef __attribute__((ext_vector_type(4))) _Float16 half4v;
typedef __attribute__((ext_vector_type(8))) _Float16 half8v;

__device__ inline unsigned int f2h15(float w) {
    half_t h = (half_t)w;
    return (unsigned int)__builtin_bit_cast(unsigned short, h) & 0x7FFFu;
}
__device__ inline float h15_2f(unsigned int bits) {
    half_t h = __builtin_bit_cast(half_t, (unsigned short)(bits & 0x7FFFu));
    return (float)h;
}

template <typename T> struct V4;
template <> struct V4<_Float16> { typedef half4v type; };
template <> struct V4<float>    { typedef float4 type; };

template <typename T>
__device__ inline float4 ld4f(const T* __restrict__ p) {
    typename V4<T>::type v = *reinterpret_cast<const typename V4<T>::type*>(p);
    float4 r;
    r.x = (float)v.x; r.y = (float)v.y; r.z = (float)v.z; r.w = (float)v.w;
    return r;
}

// 8-channel load/store helpers (16 B for fp16, 2x16 B for fp32)
__device__ inline void ld8f(const half_t* __restrict__ p, float* z) {
    half8v v = *reinterpret_cast<const half8v*>(p);
    #pragma unroll
    for (int j = 0; j < 8; ++j) z[j] = (float)v[j];
}
__device__ inline void ld8f(const float* __restrict__ p, float* z) {
    float4 a = *reinterpret_cast<const float4*>(p);
    float4 b = *reinterpret_cast<const float4*>(p + 4);
    z[0] = a.x; z[1] = a.y; z[2] = a.z; z[3] = a.w;
    z[4] = b.x; z[5] = b.y; z[6] = b.z; z[7] = b.w;
}
__device__ inline void st8(half_t* __restrict__ p, const float* r) {
    half8v v;
    #pragma unroll
    for (int j = 0; j < 8; ++j) v[j] = (half_t)r[j];
    *reinterpret_cast<half8v*>(p) = v;
}
__device__ inline void st8(float* __restrict__ p, const float* r) {
    float4 a = {r[0], r[1], r[2], r[3]};
    float4 b = {r[4], r[5], r[6], r[7]};
    *reinterpret_cast<float4*>(p) = a;
    *reinterpret_cast<float4*>(p + 4) = b;
}

// ---------------- CSR build ----------------

__global__ void hist_kernel(const int* __restrict__ dst, int* __restrict__ degI, int E) {
    int e = blockIdx.x * blockDim.x + threadIdx.x;
    if (e < E) atomicAdd(&degI[dst[e]], 1);
}

__global__ void dinv_kernel(const int* __restrict__ degI, float* __restrict__ dinv, int N) {
    int i = blockIdx.x * blockDim.x + threadIdx.x;
    if (i < N) {
        float d = (float)(degI[i] + 1);   // + self loop
        dinv[i] = rsqrtf(d);
    }
}

// rows padded to multiple of 8 slots (pad entries stay 0 => norm 0, src 0)
__global__ __launch_bounds__(256) void scan1_kernel(const int* __restrict__ degI,
                                                    int* __restrict__ rowptr,
                                                    int* __restrict__ blockSums, int N) {
    __shared__ int s[256];
    int t = threadIdx.x;
    int idx = blockIdx.x * 256 + t;
    s[t] = (idx < N) ? ((degI[idx] + 7) & ~7) : 0;
    __syncthreads();
    for (int off = 1; off < 256; off <<= 1) {
        int x = (t >= off) ? s[t - off] : 0;
        __syncthreads();
        s[t] += x;
        __syncthreads();
    }
    if (idx < N) rowptr[idx + 1] = s[t];
    if (t == 255) blockSums[blockIdx.x] = s[255];
    if (blockIdx.x == 0 && t == 0) rowptr[0] = 0;
}

__global__ __launch_bounds__(256) void scan2_kernel(int* __restrict__ blockSums, int nB) {
    __shared__ int s[256];
    int t = threadIdx.x;
    s[t] = (t < nB) ? blockSums[t] : 0;
    __syncthreads();
    for (int off = 1; off < 256; off <<= 1) {
        int x = (t >= off) ? s[t - off] : 0;
        __syncthreads();
        s[t] += x;
        __syncthreads();
    }
    if (t < nB) blockSums[t] = (t == 0) ? 0 : s[t - 1];
}

__global__ void scan3_kernel(int* __restrict__ rowptr, const int* __restrict__ blockSums,
                             int N) {
    int idx = blockIdx.x * 256 + threadIdx.x;
    if (idx < N) rowptr[idx + 1] += blockSums[blockIdx.x];
}

// edata[p] = src<<15 | fp16bits(norm) sans sign — plain store: edata is
// L2-resident (3.9 MB); NT stores forced per-store line writebacks (66 MB HBM).
__global__ void scatter_kernel(const int* __restrict__ src, const int* __restrict__ dst,
                               const int* __restrict__ rowptr, int* __restrict__ rowctr,
                               const float* __restrict__ dinv,
                               int* __restrict__ edata, int E) {
    int e = blockIdx.x * blockDim.x + threadIdx.x;
    if (e < E) {
        int d = dst[e], s = src[e];
        int p = rowptr[d] + atomicAdd(&rowctr[d], 1);
        edata[p] = (int)(((unsigned int)s << 15) | f2h15(dinv[s] * dinv[d]));
    }
}

// ---------------- fused MLP: h2 = relu(zx@W3 + v*b3^T)@W4 + b4 ----------------

__global__ __launch_bounds__(256) void fusedmlp_kernel(const half_t* __restrict__ zx,
                                                       const float* __restrict__ v,
                                                       const float* __restrict__ W3,
                                                       const float* __restrict__ b3,
                                                       const float* __restrict__ W4,
                                                       const float* __restrict__ b4,
                                                       float* __restrict__ h2, int N) {
    __shared__ float Ws[64 * 128];     // 32 KB: W3 [k][128] then W4 [k][64]
    __shared__ half_t zsT[64 * 36];    // [k][row] fp16, padded stride 36
    __shared__ half_t ts[32 * 132];    // [row][k] fp16, padded stride 132
    __shared__ float vs[32];
    int t = threadIdx.x;
    int r0 = blockIdx.x * 32;
    int rows = min(32, N - r0);

    for (int idx = t; idx < 64 * 128; idx += 256) Ws[idx] = W3[idx];
    for (int idx = t; idx < 32 * 64; idx += 256) {
        int r = idx >> 6, c = idx & 63;
        zsT[c * 36 + r] = (r < rows) ? zx[(size_t)(r0 + r) * 64 + c] : (half_t)0.0f;
    }
    if (t < 32) vs[t] = (t < rows) ? v[r0 + t] : 0.0f;
    __syncthreads();

    // ---- layer 1: ts = relu(z @ W3 + v*b3^T) ----
    {
        int cq = t & 31, rq = t >> 5;
        int cb = cq * 4, rb = rq * 4;
        float4 b3v = *reinterpret_cast<const float4*>(&b3[cb]);
        float a[4][4];
        #pragma unroll
        for (int ri = 0; ri < 4; ++ri) {
            float vv = vs[rb + ri];
            a[ri][0] = vv * b3v.x; a[ri][1] = vv * b3v.y;
            a[ri][2] = vv * b3v.z; a[ri][3] = vv * b3v.w;
        }
        #pragma unroll 4
        for (int k = 0; k < 64; ++k) {
            half4v zh = *reinterpret_cast<const half4v*>(&zsT[k * 36 + rb]);
            float z0 = (float)zh.x, z1 = (float)zh.y, z2 = (float)zh.z, z3 = (float)zh.w;
            float4 wq = *reinterpret_cast<const float4*>(&Ws[k * 128 + cb]);
            a[0][0] += z0 * wq.x; a[0][1] += z0 * wq.y;
            a[0][2] += z0 * wq.z; a[0][3] += z0 * wq.w;
            a[1][0] += z1 * wq.x; a[1][1] += z1 * wq.y;
            a[1][2] += z1 * wq.z; a[1][3] += z1 * wq.w;
            a[2][0] += z2 * wq.x; a[2][1] += z2 * wq.y;
            a[2][2] += z2 * wq.z; a[2][3] += z2 * wq.w;
            a[3][0] += z3 * wq.x; a[3][1] += z3 * wq.y;
            a[3][2] += z3 * wq.z; a[3][3] += z3 * wq.w;
        }
        #pragma unroll
        for (int ri = 0; ri < 4; ++ri) {
            half4v o;
            o.x = (half_t)fmaxf(a[ri][0], 0.0f); o.y = (half_t)fmaxf(a[ri][1], 0.0f);
            o.z = (half_t)fmaxf(a[ri][2], 0.0f); o.w = (half_t)fmaxf(a[ri][3], 0.0f);
            *reinterpret_cast<half4v*>(&ts[(rb + ri) * 132 + cb]) = o;
        }
    }
    __syncthreads();
    for (int idx = t; idx < 128 * 64; idx += 256) Ws[idx] = W4[idx];
    __syncthreads();

    // ---- layer 2: h2 = t @ W4 + b4 (row-major ts reads) ----
    {
        int cg = t & 15, rg = t >> 4;
        int cb = cg * 4, rb = rg * 2;
        float4 b4v = *reinterpret_cast<const float4*>(&b4[cb]);
        float a[2][4];
        #pragma unroll
        for (int ri = 0; ri < 2; ++ri) {
            a[ri][0] = b4v.x; a[ri][1] = b4v.y; a[ri][2] = b4v.z; a[ri][3] = b4v.w;
        }
        #pragma unroll 4
        for (int k = 0; k < 128; ++k) {
            float t0 = (float)ts[rb * 132 + k];
            float t1 = (float)ts[(rb + 1) * 132 + k];
            float4 wq = *reinterpret_cast<const float4*>(&Ws[k * 64 + cb]);
            a[0][0] += t0 * wq.x; a[0][1] += t0 * wq.y;
            a[0][2] += t0 * wq.z; a[0][3] += t0 * wq.w;
            a[1][0] += t1 * wq.x; a[1][1] += t1 * wq.y;
            a[1][2] += t1 * wq.z; a[1][3] += t1 * wq.w;
        }
        #pragma unroll
        for (int ri = 0; ri < 2; ++ri) {
            int r = rb + ri;
            if (r < rows) {
                float4 o = {a[ri][0], a[ri][1], a[ri][2], a[ri][3]};
                *reinterpret_cast<float4*>(&h2[(size_t)(r0 + r) * 64 + cb]) = o;
            }
        }
    }
}

// ---------------- propagation ----------------
// One node per wave. Lane -> (edge slot g = lane>>3, channel base c = (lane&7)*8).
// One gather instruction = 8 edges x 128 B row = 1 KB (coalescing sweet spot).
// CSR rows padded to multiple of 8 with zero-norm edges -> no tails, no masks.
// Cross-slot reduction: shfl_xor 8/16/32 (lane&7 invariant).

template <typename TI, bool WITHV>
__device__ inline void round8(const TI* __restrict__ zin, const int* __restrict__ edata,
                              int e, int g, int c, float* a, float& vacc,
                              const float* __restrict__ vin, int firstOnes) {
    unsigned int p = (unsigned int)edata[e + g];   // uniform within 8-lane group
    int s = p >> 15;
    float n = h15_2f(p);                           // pad slots: p==0 -> n==0
    float z[8];
    ld8f(&zin[(size_t)s * 64 + c], z);
    if (WITHV) vacc += firstOnes ? n : n * vin[s];
    #pragma unroll
    for (int j = 0; j < 8; ++j) a[j] += n * z[j];
}

template <typename TI, typename TO, bool WITHV>
__global__ __launch_bounds__(256) void prop64_kernel(const TI* __restrict__ zin,
                                                     const float* __restrict__ h,
                                                     const int* __restrict__ rowptr,
                                                     const int* __restrict__ edata,
                                                     const float* __restrict__ dinv,
                                                     TO* __restrict__ zout,
                                                     const float* __restrict__ vin,
                                                     float* __restrict__ vout,
                                                     int N, int firstOnes) {
    int wave = threadIdx.x >> 6;
    int lane = threadIdx.x & 63;
    int g = lane >> 3;              // edge slot 0..7
    int c = (lane & 7) << 3;        // channel base (8 channels/lane)
    int node = blockIdx.x * 4 + wave;
    if (node >= N) return;
    node = __builtin_amdgcn_readfirstlane(node);
    int beg = rowptr[node];
    int end = rowptr[node + 1];     // end-beg is a multiple of 8

    float a[8] = {0.f, 0.f, 0.f, 0.f, 0.f, 0.f, 0.f, 0.f};
    float vacc = 0.f;

    int e = beg;
    for (; e + 16 <= end; e += 16) {        // 16 edges / iter, 2 gathers in flight
        round8<TI, WITHV>(zin, edata, e, g, c, a, vacc, vin, firstOnes);
        round8<TI, WITHV>(zin, edata, e + 8, g, c, a, vacc, vin, firstOnes);
    }
    if (e < end)                            // residue is exactly 8 (padded)
        round8<TI, WITHV>(zin, edata, e, g, c, a, vacc, vin, firstOnes);

    // reduce across 8 edge slots; (lane&7) -> channel slice preserved
    #pragma unroll
    for (int m = 8; m <= 32; m <<= 1) {
        #pragma unroll
        for (int j = 0; j < 8; ++j) a[j] += __shfl_xor(a[j], m);
        if (WITHV) vacc += __shfl_xor(vacc, m);
    }

    // epilogue: lanes 0-7 hold the full row (8 channels each)
    if (lane < 8) {
        int cw = lane << 3;
        size_t base = (size_t)node * 64 + cw;
        float di = dinv[node];
        float dd = di * di;
        float self[8];
        ld8f(&zin[base], self);
        float4 h0 = *reinterpret_cast<const float4*>(&h[base]);
        float4 h1 = *reinterpret_cast<const float4*>(&h[base + 4]);
        float hh[8] = {h0.x, h0.y, h0.z, h0.w, h1.x, h1.y, h1.z, h1.w};
        float r[8];
        #pragma unroll
        for (int j = 0; j < 8; ++j)
            r[j] = (1.0f - PROP_ALPHA) * (a[j] + dd * self[j]) + PROP_ALPHA * hh[j];
        st8(&zout[base], r);
        if (WITHV && lane == 0) {
            float selfv = firstOnes ? 1.0f : vin[node];
            vout[node] = (1.0f - PROP_ALPHA) * (vacc + dd * selfv) + PROP_ALPHA;
        }
    }
}

// ---------------- launch ----------------

extern "C" void kernel_launch(void* const* d_in, const int* in_sizes, int n_in,
                              void* d_out, int out_size, void* d_ws, size_t ws_size,
                              hipStream_t stream) {
    const float* x  = (const float*)d_in[0];
    const int*   ei = (const int*)d_in[1];
    const float* W3 = (const float*)d_in[2];
    const float* b3 = (const float*)d_in[3];
    const float* W4 = (const float*)d_in[4];
    const float* b4 = (const float*)d_in[5];
    float* out = (float*)d_out;

    int N = in_sizes[0] / 64;   // IN_CH = 64
    int E = in_sizes[1] / 2;
    const int* srcA = ei;
    const int* dstA = ei + E;

    char* ws = (char*)d_ws;
    size_t off = 0;
    auto alloc = [&](size_t bytes) -> void* {
        void* p = ws + off;
        off = (off + bytes + 255) & ~(size_t)255;
        return p;
    };

    int nScanB = (N + 255) / 256;
    size_t ePadMax = (size_t)E + 8 * (size_t)N;   // upper bound on padded slots

    int*    degI   = (int*)alloc((size_t)N * 4);
    int*    rowptr = (int*)alloc(((size_t)N + 1) * 4);
    int*    rowctr = (int*)alloc((size_t)N * 4);
    int*    bsums  = (int*)alloc((size_t)nScanB * 4);
    float*  dinv   = (float*)alloc((size_t)N * 4);
    int*    edata  = (int*)alloc(ePadMax * 4);
    float*  vA     = (float*)alloc((size_t)N * 4);
    float*  vB     = (float*)alloc((size_t)N * 4);
    half_t* z16A   = (half_t*)alloc((size_t)N * 64 * 2);
    half_t* z16B   = (half_t*)alloc((size_t)N * 64 * 2);
    float*  hbuf   = (float*)alloc((size_t)N * 64 * 4);

    hipMemsetAsync(degI, 0, (size_t)N * 4, stream);
    hipMemsetAsync(rowctr, 0, (size_t)N * 4, stream);
    hipMemsetAsync(edata, 0, ePadMax * 4, stream);   // pad slots read as norm=0

    // --- CSR build (padded rows) ---
    hist_kernel<<<(E + 255) / 256, 256, 0, stream>>>(dstA, degI, E);
    dinv_kernel<<<(N + 255) / 256, 256, 0, stream>>>(degI, dinv, N);
    scan1_kernel<<<nScanB, 256, 0, stream>>>(degI, rowptr, bsums, N);
    scan2_kernel<<<1, 256, 0, stream>>>(bsums, nScanB);
    scan3_kernel<<<nScanB, 256, 0, stream>>>(rowptr, bsums, N);
    scatter_kernel<<<(E + 255) / 256, 256, 0, stream>>>(srcA, dstA, rowptr, rowctr,
                                                        dinv, edata, E);

    int propBlocks = (N + 3) / 4;   // one node per wave, 4 waves per block

    // --- prop1: zx = M*x, z fp16 between steps, fused v = M*ones ---
    for (int s = 0; s < PROP_KSTEPS; ++s) {
        const float* vi = (s & 1) ? vA : vB;   // s0: unused (firstOnes)
        float*       vo = (s & 1) ? vB : vA;
        if (s == 0) vi = vB;
        if (s == 0) {
            prop64_kernel<float, half_t, true><<<propBlocks, 256, 0, stream>>>(
                x, x, rowptr, edata, dinv, z16A, vi, vo, N, 1);
        } else {
            const half_t* in = (s & 1) ? z16A : z16B;
            half_t*       o  = (s & 1) ? z16B : z16A;
            prop64_kernel<half_t, half_t, true><<<propBlocks, 256, 0, stream>>>(
                in, x, rowptr, edata, dinv, o, vi, vo, N, 0);
        }
    }
    // zx (fp16) in z16B, v in vB

    // --- h2 = relu(zx@W3 + v*b3^T)@W4 + b4 ---
    fusedmlp_kernel<<<(N + 31) / 32, 256, 0, stream>>>(z16B, vB, W3, b3, W4, b4, hbuf, N);

    // --- prop2: out = M*h2 ---
    for (int s = 0; s < PROP_KSTEPS; ++s) {
        if (s == 0) {
            prop64_kernel<float, half_t, false><<<propBlocks, 256, 0, stream>>>(
                hbuf, hbuf, rowptr, edata, dinv, z16A, nullptr, nullptr, N, 0);
        } else if (s == PROP_KSTEPS - 1) {
            prop64_kernel<half_t, float, false><<<propBlocks, 256, 0, stream>>>(
                z16A, hbuf, rowptr, edata, dinv, out, nullptr, nullptr, N, 0);
        } else {
            const half_t* in = (s & 1) ? z16A : z16B;
            half_t*       o  = (s & 1) ? z16B : z16A;
            prop64_kernel<half_t, half_t, false><<<propBlocks, 256, 0, stream>>>(
                in, hbuf, rowptr, edata, dinv, o, nullptr, nullptr, N, 0);
        }
    }
}